// Round 11
// baseline (116.519 us; speedup 1.0000x reference)
//
#include <hip/hip_runtime.h>
#include <hip/hip_fp16.h>
#include <math.h>

#define BDIM 4
#define LDIM 512
#define EDIM 1024
#define HDIM 128
#define TILE 32            // 32x32 y-tile, 33x33 s-grid (1 halo), grid 16x16x4
#define NT   16
#define K2   2.885390081777927f   // 2/ln(2)

typedef unsigned short ushort_t;
typedef __attribute__((ext_vector_type(8))) _Float16 half8;
typedef __attribute__((ext_vector_type(4))) float f32x4;

struct __align__(16) H8 { __half2 p[4]; };
union HU { H8 h; half8 v; };
struct __align__(8) US4 { ushort_t u[4]; };

// ---------------------------------------------------------------------------
// Kernel 1 (round-9/10 exact): LDS-staged GEMM, 512-thread blocks.
// hid = relu(emb @ W1 + b1) f16 (rec rows * -K2). 256 blocks = 1 block/CU,
// 8 waves = 2 waves/SIMD. Block 0 also preps wneg[16][128] + wsumg[4].
// ---------------------------------------------------------------------------
__global__ __launch_bounds__(512) void gemm_lds(
    const float* __restrict__ rec, const float* __restrict__ lig,
    const float* __restrict__ W1, const float* __restrict__ b1,
    const float* __restrict__ cw, ushort_t* __restrict__ hid,
    ushort_t* __restrict__ wneg, float* __restrict__ wsumg) {
  __shared__ ushort_t Al[16][1026];        // 32.8 KB, row stride 513 dw (odd)
  __shared__ ushort_t Bl[2][128][130];     // 66.6 KB, row stride 65 dw (odd)
  __shared__ float wp[2][4];

  const int t = threadIdx.x;

  if (blockIdx.x == 0) {                   // fold wneg/wsumg prep into block 0
    if (t < HDIM) {
      float4 w4 = *(const float4*)&cw[t * 4];
      _Float16 h0 = (_Float16)(-2.f * w4.x), h1 = (_Float16)(-2.f * w4.y);
      _Float16 h2 = (_Float16)(-2.f * w4.z), h3 = (_Float16)(-2.f * w4.w);
      wneg[0 * HDIM + t] = *(ushort_t*)&h0;
      wneg[1 * HDIM + t] = *(ushort_t*)&h1;
      wneg[2 * HDIM + t] = *(ushort_t*)&h2;
      wneg[3 * HDIM + t] = *(ushort_t*)&h3;
#pragma unroll
      for (int k = 4; k < 16; ++k) wneg[k * HDIM + t] = 0;
      float4 ws = w4;
#pragma unroll
      for (int off = 32; off > 0; off >>= 1) {
        ws.x += __shfl_down(ws.x, off, 64);
        ws.y += __shfl_down(ws.y, off, 64);
        ws.z += __shfl_down(ws.z, off, 64);
        ws.w += __shfl_down(ws.w, off, 64);
      }
      if ((t & 63) == 0) {
        wp[t >> 6][0] = ws.x; wp[t >> 6][1] = ws.y;
        wp[t >> 6][2] = ws.z; wp[t >> 6][3] = ws.w;
      }
    }
    __syncthreads();
    if (t < 4) wsumg[t] = wp[0][t] + wp[1][t];
  }

  const int r0 = (int)blockIdx.x * 16;     // strip rows r0..r0+15
  const float* abase = (r0 < BDIM * LDIM)
                           ? rec + (size_t)r0 * EDIM
                           : lig + (size_t)(r0 - BDIM * LDIM) * EDIM;

  // ---- stage A strip: 16 rows x 1024 f32 -> f16. thread t: row t>>5,
  // cols (t&31)*4 + p*128 (32 lanes x 16B contiguous per row).
  {
    const int sr = t >> 5, su = t & 31;
    const float* ar = abase + (size_t)sr * EDIM;
#pragma unroll
    for (int p = 0; p < 8; ++p) {
      const int c = su * 4 + p * 128;
      f32x4 v = *(const f32x4*)(ar + c);
      *(__half2*)&Al[sr][c] = __floats2half2_rn(v[0], v[1]);
      *(__half2*)&Al[sr][c + 2] = __floats2half2_rn(v[2], v[3]);
    }
  }

  // ---- stage B chunk 0: rows 0..127 of W1 -> Bl[0] transposed [col][k].
  // thread t: k-pair kp = p*16 + (t>>5), cols (t&31)*4..+3, p in 0..3.
  const int cu4 = (t & 31) * 4, kg = t >> 5;
  {
#pragma unroll
    for (int p = 0; p < 4; ++p) {
      const int kp = p * 16 + kg;
      f32x4 ra = *(const f32x4*)(W1 + (size_t)(2 * kp) * HDIM + cu4);
      f32x4 rb = *(const f32x4*)(W1 + (size_t)(2 * kp + 1) * HDIM + cu4);
#pragma unroll
      for (int i = 0; i < 4; ++i)
        *(__half2*)&Bl[0][cu4 + i][2 * kp] = __floats2half2_rn(ra[i], rb[i]);
    }
  }
  __syncthreads();

  const int w = t >> 6, l = t & 63;        // 8 waves
  const int m = l & 15, q = l >> 4;
  const int tc0 = 16 * w;                  // wave's 16-col tile

  f32x4 acc = {0.f, 0.f, 0.f, 0.f};
  for (int kc = 0; kc < 8; ++kc) {
    const int bb = kc & 1;
    f32x4 sa[4], sb[4];
    if (kc < 7) {                          // prefetch next chunk to regs
      const float* wb = W1 + (size_t)((kc + 1) * 128) * HDIM;
#pragma unroll
      for (int p = 0; p < 4; ++p) {
        const int kp = p * 16 + kg;
        sa[p] = *(const f32x4*)(wb + (size_t)(2 * kp) * HDIM + cu4);
        sb[p] = *(const f32x4*)(wb + (size_t)(2 * kp + 1) * HDIM + cu4);
      }
    }
#pragma unroll
    for (int s = 0; s < 4; ++s) {
      const int kof = s * 32 + q * 8;
      half8 af = *(const half8*)&Al[m][kc * 128 + kof];
      half8 bf = *(const half8*)&Bl[bb][tc0 + m][kof];
      acc = __builtin_amdgcn_mfma_f32_16x16x32_f16(af, bf, acc, 0, 0, 0);
    }
    if (kc < 7) {                          // drain prefetch into other buffer
#pragma unroll
      for (int p = 0; p < 4; ++p) {
        const int kp = p * 16 + kg;
#pragma unroll
        for (int i = 0; i < 4; ++i)
          *(__half2*)&Bl[bb ^ 1][cu4 + i][2 * kp] =
              __floats2half2_rn(sa[p][i], sb[p][i]);
      }
    }
    __syncthreads();
  }

  const float scale = (r0 < BDIM * LDIM) ? -K2 : 1.0f;
  const float bias = b1[tc0 + m];
#pragma unroll
  for (int r = 0; r < 4; ++r) {
    const int row = r0 + q * 4 + r;
    float v = fmaxf(acc[r] + bias, 0.f) * scale;
    ((_Float16*)hid)[(size_t)row * HDIM + tc0 + m] = (_Float16)v;
  }
}

// ---------------------------------------------------------------------------
// Kernel 2: 32x32 y-tile, 512-thread/8-wave blocks, grid 1024, (512,4).
// SINGLE CHANGE vs round 10: phase B loop interchange hf-outer -> c-outer.
// r-row reads are hf-invariant: old order read them twice (32 of 40 b128
// reads/thread); new order reads r once per c-chunk (24 total) and runs
// 8 independent GCHAIN chains per iteration (4 rows x 2 j-halves, was 4),
// doubling exp-chain ILP into the quarter-rate trans pipe. Accs double to
// 8xf32x4 (32 VGPR; budget fits 128). Per-acc op order unchanged ->
// bit-identical sl4/absmax. Staging/edge/phase C byte-identical.
// ---------------------------------------------------------------------------
__global__ __launch_bounds__(512, 4) void bilinear_max(
    const ushort_t* __restrict__ hid, const ushort_t* __restrict__ wneg,
    const float* __restrict__ wsumg, const float* __restrict__ cw,
    const float* __restrict__ cb, float* __restrict__ partial) {
  __shared__ ushort_t rl[33][130];     // 65-dword row stride
  __shared__ ushort_t ll[33][130];
  __shared__ ushort_t sl4[33][34][4];  // f16 taps {s00,s01,s10,s11}
  __shared__ float wred[8];

  const int t = threadIdx.x;
  const int b = blockIdx.z;
  const int ib = (int)blockIdx.y * TILE - 1;
  const int jb = (int)blockIdx.x * TILE - 1;
  const int w = t >> 6, l = t & 63;
  const int q = l >> 4, c15 = l & 15;

  half8 wf[4];
#pragma unroll
  for (int c = 0; c < 4; ++c)
    wf[c] = *(const half8*)&wneg[c15 * HDIM + c * 32 + q * 8];
  const float wsum_v = (c15 < 4) ? wsumg[c15] : 0.f;

  // stage 33+33 rows x 16 octets
  H8 z;
  z.p[0] = z.p[1] = z.p[2] = z.p[3] = __floats2half2_rn(0.f, 0.f);
  for (int p = t; p < 66 * 16; p += 512) {
    int r = p >> 4, seg = (p & 15) * 8;
    if (r < 33) {
      int i = ib + r;
      H8 v = z;
      if (i >= 0) v = *(const H8*)&hid[((size_t)(b * LDIM + i)) * HDIM + seg];
      *(H8*)&rl[r][seg] = v;
    } else {
      int j = jb + (r - 33);
      H8 v = z;
      if (j >= 0) v = *(const H8*)&hid[((size_t)((BDIM + b) * LDIM + j)) * HDIM + seg];
      *(H8*)&ll[r - 33][seg] = v;
    }
  }
  __syncthreads();

  const __half2 E0 = __float2half2_rn(0.991381f);
  const __half2 E1 = __float2half2_rn(-0.818328f);
  const __half2 E2 = __float2half2_rn(0.333048f);
#define POLYG(U) __hmul2(U, __hfma2(U, __hfma2(U, E2, E1), E0))
#define GCHAIN(GU, RU, LU)                                                    \
  {                                                                           \
    __half2 u0 = h2exp2(__hmul2((RU).h.p[0], (LU).h.p[0]));                   \
    __half2 u1 = h2exp2(__hmul2((RU).h.p[1], (LU).h.p[1]));                   \
    __half2 u2 = h2exp2(__hmul2((RU).h.p[2], (LU).h.p[2]));                   \
    __half2 u3 = h2exp2(__hmul2((RU).h.p[3], (LU).h.p[3]));                   \
    (GU).h.p[0] = POLYG(u0);                                                  \
    (GU).h.p[1] = POLYG(u1);                                                  \
    (GU).h.p[2] = POLYG(u2);                                                  \
    (GU).h.p[3] = POLYG(u3);                                                  \
  }

  // phase B (c-outer): wave w covers rows ii..ii+3; both j-halves per c.
  const int ii = w * 4;
  f32x4 a00 = {0.f, 0.f, 0.f, 0.f}, a01 = a00, a02 = a00, a03 = a00;
  f32x4 a10 = a00, a11 = a00, a12 = a00, a13 = a00;
#pragma unroll
  for (int c = 0; c < 4; ++c) {
    const int co = c * 32 + q * 8;
    HU r0, r1, r2, r3, lu0, lu1;
    r0.v = *(const half8*)&rl[ii + 0][co];
    r1.v = *(const half8*)&rl[ii + 1][co];
    r2.v = *(const half8*)&rl[ii + 2][co];
    r3.v = *(const half8*)&rl[ii + 3][co];
    lu0.v = *(const half8*)&ll[c15][co];         // hf=0 (jj0=0)
    lu1.v = *(const half8*)&ll[16 + c15][co];    // hf=1 (jj0=16)
    HU g00, g01, g02, g03, g10, g11, g12, g13;
    GCHAIN(g00, r0, lu0)
    GCHAIN(g01, r1, lu0)
    GCHAIN(g02, r2, lu0)
    GCHAIN(g03, r3, lu0)
    GCHAIN(g10, r0, lu1)
    GCHAIN(g11, r1, lu1)
    GCHAIN(g12, r2, lu1)
    GCHAIN(g13, r3, lu1)
    a00 = __builtin_amdgcn_mfma_f32_16x16x32_f16(g00.v, wf[c], a00, 0, 0, 0);
    a01 = __builtin_amdgcn_mfma_f32_16x16x32_f16(g01.v, wf[c], a01, 0, 0, 0);
    a02 = __builtin_amdgcn_mfma_f32_16x16x32_f16(g02.v, wf[c], a02, 0, 0, 0);
    a03 = __builtin_amdgcn_mfma_f32_16x16x32_f16(g03.v, wf[c], a03, 0, 0, 0);
    a10 = __builtin_amdgcn_mfma_f32_16x16x32_f16(g10.v, wf[c], a10, 0, 0, 0);
    a11 = __builtin_amdgcn_mfma_f32_16x16x32_f16(g11.v, wf[c], a11, 0, 0, 0);
    a12 = __builtin_amdgcn_mfma_f32_16x16x32_f16(g12.v, wf[c], a12, 0, 0, 0);
    a13 = __builtin_amdgcn_mfma_f32_16x16x32_f16(g13.v, wf[c], a13, 0, 0, 0);
  }
  if (c15 < 4) {
#pragma unroll
    for (int r = 0; r < 4; ++r) {
      const int col0 = q * 4 + r;          // hf=0 cols 0..15
      _Float16 h00 = (_Float16)(wsum_v + a00[r]);
      _Float16 h01 = (_Float16)(wsum_v + a01[r]);
      _Float16 h02 = (_Float16)(wsum_v + a02[r]);
      _Float16 h03 = (_Float16)(wsum_v + a03[r]);
      sl4[ii + 0][col0][c15] = *(ushort_t*)&h00;
      sl4[ii + 1][col0][c15] = *(ushort_t*)&h01;
      sl4[ii + 2][col0][c15] = *(ushort_t*)&h02;
      sl4[ii + 3][col0][c15] = *(ushort_t*)&h03;
      const int col1 = 16 + q * 4 + r;     // hf=1 cols 16..31
      _Float16 h10 = (_Float16)(wsum_v + a10[r]);
      _Float16 h11 = (_Float16)(wsum_v + a11[r]);
      _Float16 h12 = (_Float16)(wsum_v + a12[r]);
      _Float16 h13 = (_Float16)(wsum_v + a13[r]);
      sl4[ii + 0][col1][c15] = *(ushort_t*)&h10;
      sl4[ii + 1][col1][c15] = *(ushort_t*)&h11;
      sl4[ii + 2][col1][c15] = *(ushort_t*)&h12;
      sl4[ii + 3][col1][c15] = *(ushort_t*)&h13;
    }
  }
#undef GCHAIN
#undef POLYG

  // edge strips (no barrier needed: disjoint sl4 region from phase B).
  // 65 pairs x 4 lanes (32 h each) over threads 0..259, shfl_xor reduce.
  if (t < 260) {
    const int pr = t >> 2;
    const int o = t & 3;
    const int pi = (pr < 33) ? pr : 32;
    const int qj = (pr < 33) ? 32 : (pr - 33);
    float sa0 = 0.f, sa1 = 0.f, sa2 = 0.f, sa3 = 0.f;
    const int hb = o * 32;
    for (int h8 = hb; h8 < hb + 32; h8 += 8) {
      HU r8, l8;
      r8.v = *(const half8*)&rl[pi][h8];
      l8.v = *(const half8*)&ll[qj][h8];
#pragma unroll
      for (int j = 0; j < 4; ++j) {
        float2 pf = __half22float2(__hmul2(r8.h.p[j], l8.h.p[j]));
        float u0 = __builtin_amdgcn_exp2f(pf.x);
        float u1 = __builtin_amdgcn_exp2f(pf.y);
        float g0 = u0 * fmaf(u0, fmaf(u0, 0.333048f, -0.818328f), 0.991381f);
        float g1 = u1 * fmaf(u1, fmaf(u1, 0.333048f, -0.818328f), 0.991381f);
        float4 wa = *(const float4*)&cw[(h8 + 2 * j) * 4];
        float4 wb = *(const float4*)&cw[(h8 + 2 * j + 1) * 4];
        sa0 = fmaf(-2.f * g0, wa.x, fmaf(-2.f * g1, wb.x, sa0));
        sa1 = fmaf(-2.f * g0, wa.y, fmaf(-2.f * g1, wb.y, sa1));
        sa2 = fmaf(-2.f * g0, wa.z, fmaf(-2.f * g1, wb.z, sa2));
        sa3 = fmaf(-2.f * g0, wa.w, fmaf(-2.f * g1, wb.w, sa3));
      }
    }
    sa0 += __shfl_xor(sa0, 1, 64);
    sa1 += __shfl_xor(sa1, 1, 64);
    sa2 += __shfl_xor(sa2, 1, 64);
    sa3 += __shfl_xor(sa3, 1, 64);
    sa0 += __shfl_xor(sa0, 2, 64);
    sa1 += __shfl_xor(sa1, 2, 64);
    sa2 += __shfl_xor(sa2, 2, 64);
    sa3 += __shfl_xor(sa3, 2, 64);
    if (o == 0) {
      _Float16 h0 = (_Float16)(wsumg[0] + sa0);
      _Float16 h1 = (_Float16)(wsumg[1] + sa1);
      _Float16 h2 = (_Float16)(wsumg[2] + sa2);
      _Float16 h3 = (_Float16)(wsumg[3] + sa3);
      US4 s;
      s.u[0] = *(ushort_t*)&h0; s.u[1] = *(ushort_t*)&h1;
      s.u[2] = *(ushort_t*)&h2; s.u[3] = *(ushort_t*)&h3;
      *(US4*)&sl4[pi][qj][0] = s;
    }
  }
  __syncthreads();

  // phase C: y = cb + s00(iy-1,jj-1)+s01(iy-1,jj)+s10(iy,jj-1)+s11(iy,jj)
  float m = -INFINITY;
  const float cbv = cb[0];
  for (int p = t; p < TILE * TILE; p += 512) {
    int jj = (p & 31) + 1, iy = (p >> 5) + 1;
    float v = cbv + (float)(*(const _Float16*)&sl4[iy - 1][jj - 1][0])
                  + (float)(*(const _Float16*)&sl4[iy - 1][jj][1])
                  + (float)(*(const _Float16*)&sl4[iy][jj - 1][2])
                  + (float)(*(const _Float16*)&sl4[iy][jj][3]);
    m = fmaxf(m, v);
  }
#pragma unroll
  for (int off = 32; off > 0; off >>= 1) m = fmaxf(m, __shfl_down(m, off, 64));
  if ((t & 63) == 0) wred[t >> 6] = m;
  __syncthreads();
  if (t == 0) {
    float mm = wred[0];
#pragma unroll
    for (int i = 1; i < 8; ++i) mm = fmaxf(mm, wred[i]);
    partial[((size_t)b * NT + blockIdx.y) * NT + blockIdx.x] = mm;
  }
}

// ---------------------------------------------------------------------------
// Kernel 3: reduce 16x16 partials per batch, sigmoid, write 4 outputs.
// ---------------------------------------------------------------------------
__global__ __launch_bounds__(64) void finalize(const float* __restrict__ partial,
                                               float* __restrict__ out) {
  const int b = blockIdx.x, t = threadIdx.x;
  float m = -INFINITY;
  for (int p = t; p < NT * NT; p += 64) m = fmaxf(m, partial[b * NT * NT + p]);
#pragma unroll
  for (int off = 32; off > 0; off >>= 1) m = fmaxf(m, __shfl_down(m, off, 64));
  if (t == 0) out[b] = 1.f / (1.f + expf(-m));
}

extern "C" void kernel_launch(void* const* d_in, const int* in_sizes, int n_in,
                              void* d_out, int out_size, void* d_ws, size_t ws_size,
                              hipStream_t stream) {
  const float* rec = (const float*)d_in[0];
  const float* lig = (const float*)d_in[1];
  const float* W1  = (const float*)d_in[2];
  const float* b1  = (const float*)d_in[3];
  const float* cw  = (const float*)d_in[4];   // (1,H,2,2): {w00,w01,w10,w11} per h
  const float* cb  = (const float*)d_in[5];
  float* out = (float*)d_out;

  ushort_t* hid  = (ushort_t*)d_ws;                        // 4096x128 f16 = 1 MB
  float* partial = (float*)(hid + (size_t)2 * BDIM * LDIM * HDIM);  // 1024 f32
  ushort_t* wneg = (ushort_t*)(partial + NT * NT * BDIM);  // 16x128 f16 = 4 KB
  float* wsumg   = (float*)(wneg + 16 * HDIM);             // 4 f32

  gemm_lds<<<dim3(256), 512, 0, stream>>>(rec, lig, W1, b1, cw, hid, wneg, wsumg);
  bilinear_max<<<dim3(NT, NT, BDIM), 512, 0, stream>>>(hid, wneg, wsumg, cw, cb, partial);
  finalize<<<dim3(BDIM), 64, 0, stream>>>(partial, out);
}

// Round 12
// 114.352 us; speedup vs baseline: 1.0189x; 1.0189x over previous
//
#include <hip/hip_runtime.h>
#include <hip/hip_fp16.h>
#include <math.h>

#define BDIM 4
#define LDIM 512
#define EDIM 1024
#define HDIM 128
#define TILE 32            // 32x32 y-tile, 33x33 s-grid (1 halo), grid 16x16x4
#define NT   16
#define K2   2.885390081777927f   // 2/ln(2)

typedef unsigned short ushort_t;
typedef __attribute__((ext_vector_type(8))) _Float16 half8;
typedef __attribute__((ext_vector_type(4))) float f32x4;

struct __align__(16) H8 { __half2 p[4]; };
union HU { H8 h; half8 v; };
struct __align__(8) US4 { ushort_t u[4]; };

// ---------------------------------------------------------------------------
// Kernel 1 (round-9/10 exact): LDS-staged GEMM, 512-thread blocks.
// hid = relu(emb @ W1 + b1) f16 (rec rows * -K2). 256 blocks = 1 block/CU,
// 8 waves = 2 waves/SIMD. Block 0 also preps wneg[16][128] + wsumg[4].
// ---------------------------------------------------------------------------
__global__ __launch_bounds__(512) void gemm_lds(
    const float* __restrict__ rec, const float* __restrict__ lig,
    const float* __restrict__ W1, const float* __restrict__ b1,
    const float* __restrict__ cw, ushort_t* __restrict__ hid,
    ushort_t* __restrict__ wneg, float* __restrict__ wsumg) {
  __shared__ ushort_t Al[16][1026];        // 32.8 KB, row stride 513 dw (odd)
  __shared__ ushort_t Bl[2][128][130];     // 66.6 KB, row stride 65 dw (odd)
  __shared__ float wp[2][4];

  const int t = threadIdx.x;

  if (blockIdx.x == 0) {                   // fold wneg/wsumg prep into block 0
    if (t < HDIM) {
      float4 w4 = *(const float4*)&cw[t * 4];
      _Float16 h0 = (_Float16)(-2.f * w4.x), h1 = (_Float16)(-2.f * w4.y);
      _Float16 h2 = (_Float16)(-2.f * w4.z), h3 = (_Float16)(-2.f * w4.w);
      wneg[0 * HDIM + t] = *(ushort_t*)&h0;
      wneg[1 * HDIM + t] = *(ushort_t*)&h1;
      wneg[2 * HDIM + t] = *(ushort_t*)&h2;
      wneg[3 * HDIM + t] = *(ushort_t*)&h3;
#pragma unroll
      for (int k = 4; k < 16; ++k) wneg[k * HDIM + t] = 0;
      float4 ws = w4;
#pragma unroll
      for (int off = 32; off > 0; off >>= 1) {
        ws.x += __shfl_down(ws.x, off, 64);
        ws.y += __shfl_down(ws.y, off, 64);
        ws.z += __shfl_down(ws.z, off, 64);
        ws.w += __shfl_down(ws.w, off, 64);
      }
      if ((t & 63) == 0) {
        wp[t >> 6][0] = ws.x; wp[t >> 6][1] = ws.y;
        wp[t >> 6][2] = ws.z; wp[t >> 6][3] = ws.w;
      }
    }
    __syncthreads();
    if (t < 4) wsumg[t] = wp[0][t] + wp[1][t];
  }

  const int r0 = (int)blockIdx.x * 16;     // strip rows r0..r0+15
  const float* abase = (r0 < BDIM * LDIM)
                           ? rec + (size_t)r0 * EDIM
                           : lig + (size_t)(r0 - BDIM * LDIM) * EDIM;

  // ---- stage A strip: 16 rows x 1024 f32 -> f16. thread t: row t>>5,
  // cols (t&31)*4 + p*128 (32 lanes x 16B contiguous per row).
  {
    const int sr = t >> 5, su = t & 31;
    const float* ar = abase + (size_t)sr * EDIM;
#pragma unroll
    for (int p = 0; p < 8; ++p) {
      const int c = su * 4 + p * 128;
      f32x4 v = *(const f32x4*)(ar + c);
      *(__half2*)&Al[sr][c] = __floats2half2_rn(v[0], v[1]);
      *(__half2*)&Al[sr][c + 2] = __floats2half2_rn(v[2], v[3]);
    }
  }

  // ---- stage B chunk 0: rows 0..127 of W1 -> Bl[0] transposed [col][k].
  // thread t: k-pair kp = p*16 + (t>>5), cols (t&31)*4..+3, p in 0..3.
  const int cu4 = (t & 31) * 4, kg = t >> 5;
  {
#pragma unroll
    for (int p = 0; p < 4; ++p) {
      const int kp = p * 16 + kg;
      f32x4 ra = *(const f32x4*)(W1 + (size_t)(2 * kp) * HDIM + cu4);
      f32x4 rb = *(const f32x4*)(W1 + (size_t)(2 * kp + 1) * HDIM + cu4);
#pragma unroll
      for (int i = 0; i < 4; ++i)
        *(__half2*)&Bl[0][cu4 + i][2 * kp] = __floats2half2_rn(ra[i], rb[i]);
    }
  }
  __syncthreads();

  const int w = t >> 6, l = t & 63;        // 8 waves
  const int m = l & 15, q = l >> 4;
  const int tc0 = 16 * w;                  // wave's 16-col tile

  f32x4 acc = {0.f, 0.f, 0.f, 0.f};
  for (int kc = 0; kc < 8; ++kc) {
    const int bb = kc & 1;
    f32x4 sa[4], sb[4];
    if (kc < 7) {                          // prefetch next chunk to regs
      const float* wb = W1 + (size_t)((kc + 1) * 128) * HDIM;
#pragma unroll
      for (int p = 0; p < 4; ++p) {
        const int kp = p * 16 + kg;
        sa[p] = *(const f32x4*)(wb + (size_t)(2 * kp) * HDIM + cu4);
        sb[p] = *(const f32x4*)(wb + (size_t)(2 * kp + 1) * HDIM + cu4);
      }
    }
#pragma unroll
    for (int s = 0; s < 4; ++s) {
      const int kof = s * 32 + q * 8;
      half8 af = *(const half8*)&Al[m][kc * 128 + kof];
      half8 bf = *(const half8*)&Bl[bb][tc0 + m][kof];
      acc = __builtin_amdgcn_mfma_f32_16x16x32_f16(af, bf, acc, 0, 0, 0);
    }
    if (kc < 7) {                          // drain prefetch into other buffer
#pragma unroll
      for (int p = 0; p < 4; ++p) {
        const int kp = p * 16 + kg;
#pragma unroll
        for (int i = 0; i < 4; ++i)
          *(__half2*)&Bl[bb ^ 1][cu4 + i][2 * kp] =
              __floats2half2_rn(sa[p][i], sb[p][i]);
      }
    }
    __syncthreads();
  }

  const float scale = (r0 < BDIM * LDIM) ? -K2 : 1.0f;
  const float bias = b1[tc0 + m];
#pragma unroll
  for (int r = 0; r < 4; ++r) {
    const int row = r0 + q * 4 + r;
    float v = fmaxf(acc[r] + bias, 0.f) * scale;
    ((_Float16*)hid)[(size_t)row * HDIM + tc0 + m] = (_Float16)v;
  }
}

// ---------------------------------------------------------------------------
// Kernel 2 (round-10 exact, confirmed best): 32x32 y-tile, 512-thread/8-wave
// blocks, grid 1024, launch_bounds(512,4) (128 VGPR, 2 blocks/CU = 16
// waves/CU). Wave w covers ii in [4w,4w+4), hf-outer loop. Edge strips
// 4x-parallel, barrier-free. [Falsified levers: setprio(-), atomic fusion(-),
// (512,8) VGPR cap(-2us), c-outer interchange(-4us), occupancy>50%(0).]
// ---------------------------------------------------------------------------
__global__ __launch_bounds__(512, 4) void bilinear_max(
    const ushort_t* __restrict__ hid, const ushort_t* __restrict__ wneg,
    const float* __restrict__ wsumg, const float* __restrict__ cw,
    const float* __restrict__ cb, float* __restrict__ partial) {
  __shared__ ushort_t rl[33][130];     // 65-dword row stride
  __shared__ ushort_t ll[33][130];
  __shared__ ushort_t sl4[33][34][4];  // f16 taps {s00,s01,s10,s11}
  __shared__ float wred[8];

  const int t = threadIdx.x;
  const int b = blockIdx.z;
  const int ib = (int)blockIdx.y * TILE - 1;
  const int jb = (int)blockIdx.x * TILE - 1;
  const int w = t >> 6, l = t & 63;
  const int q = l >> 4, c15 = l & 15;

  half8 wf[4];
#pragma unroll
  for (int c = 0; c < 4; ++c)
    wf[c] = *(const half8*)&wneg[c15 * HDIM + c * 32 + q * 8];
  const float wsum_v = (c15 < 4) ? wsumg[c15] : 0.f;

  // stage 33+33 rows x 16 octets
  H8 z;
  z.p[0] = z.p[1] = z.p[2] = z.p[3] = __floats2half2_rn(0.f, 0.f);
  for (int p = t; p < 66 * 16; p += 512) {
    int r = p >> 4, seg = (p & 15) * 8;
    if (r < 33) {
      int i = ib + r;
      H8 v = z;
      if (i >= 0) v = *(const H8*)&hid[((size_t)(b * LDIM + i)) * HDIM + seg];
      *(H8*)&rl[r][seg] = v;
    } else {
      int j = jb + (r - 33);
      H8 v = z;
      if (j >= 0) v = *(const H8*)&hid[((size_t)((BDIM + b) * LDIM + j)) * HDIM + seg];
      *(H8*)&ll[r - 33][seg] = v;
    }
  }
  __syncthreads();

  const __half2 E0 = __float2half2_rn(0.991381f);
  const __half2 E1 = __float2half2_rn(-0.818328f);
  const __half2 E2 = __float2half2_rn(0.333048f);
#define POLYG(U) __hmul2(U, __hfma2(U, __hfma2(U, E2, E1), E0))
#define GCHAIN(GU, RU, LU)                                                    \
  {                                                                           \
    __half2 u0 = h2exp2(__hmul2((RU).h.p[0], (LU).h.p[0]));                   \
    __half2 u1 = h2exp2(__hmul2((RU).h.p[1], (LU).h.p[1]));                   \
    __half2 u2 = h2exp2(__hmul2((RU).h.p[2], (LU).h.p[2]));                   \
    __half2 u3 = h2exp2(__hmul2((RU).h.p[3], (LU).h.p[3]));                   \
    (GU).h.p[0] = POLYG(u0);                                                  \
    (GU).h.p[1] = POLYG(u1);                                                  \
    (GU).h.p[2] = POLYG(u2);                                                  \
    (GU).h.p[3] = POLYG(u3);                                                  \
  }

  // phase B: wave w covers ii in [4w, 4w+4); 4 independent chains.
#pragma unroll
  for (int hf = 0; hf < 2; ++hf) {
    const int jj0 = hf << 4;
    HU lu[4];
#pragma unroll
    for (int c = 0; c < 4; ++c)
      lu[c].v = *(const half8*)&ll[jj0 + c15][c * 32 + q * 8];
    const int ii = w * 4;
    f32x4 a0 = {0.f, 0.f, 0.f, 0.f}, a1 = a0, a2 = a0, a3 = a0;
#pragma unroll
    for (int c = 0; c < 4; ++c) {
      HU r0, r1, r2, r3, g0, g1, g2, g3;
      r0.v = *(const half8*)&rl[ii + 0][c * 32 + q * 8];
      r1.v = *(const half8*)&rl[ii + 1][c * 32 + q * 8];
      r2.v = *(const half8*)&rl[ii + 2][c * 32 + q * 8];
      r3.v = *(const half8*)&rl[ii + 3][c * 32 + q * 8];
      GCHAIN(g0, r0, lu[c])
      GCHAIN(g1, r1, lu[c])
      GCHAIN(g2, r2, lu[c])
      GCHAIN(g3, r3, lu[c])
      a0 = __builtin_amdgcn_mfma_f32_16x16x32_f16(g0.v, wf[c], a0, 0, 0, 0);
      a1 = __builtin_amdgcn_mfma_f32_16x16x32_f16(g1.v, wf[c], a1, 0, 0, 0);
      a2 = __builtin_amdgcn_mfma_f32_16x16x32_f16(g2.v, wf[c], a2, 0, 0, 0);
      a3 = __builtin_amdgcn_mfma_f32_16x16x32_f16(g3.v, wf[c], a3, 0, 0, 0);
    }
    if (c15 < 4) {
#pragma unroll
      for (int r = 0; r < 4; ++r) {
        _Float16 h0 = (_Float16)(wsum_v + a0[r]);
        _Float16 h1 = (_Float16)(wsum_v + a1[r]);
        _Float16 h2 = (_Float16)(wsum_v + a2[r]);
        _Float16 h3 = (_Float16)(wsum_v + a3[r]);
        sl4[ii + 0][jj0 + q * 4 + r][c15] = *(ushort_t*)&h0;
        sl4[ii + 1][jj0 + q * 4 + r][c15] = *(ushort_t*)&h1;
        sl4[ii + 2][jj0 + q * 4 + r][c15] = *(ushort_t*)&h2;
        sl4[ii + 3][jj0 + q * 4 + r][c15] = *(ushort_t*)&h3;
      }
    }
  }
#undef GCHAIN
#undef POLYG

  // edge strips (no barrier needed: disjoint sl4 region from phase B).
  // 65 pairs x 4 lanes (32 h each) over threads 0..259, shfl_xor reduce.
  if (t < 260) {
    const int pr = t >> 2;
    const int o = t & 3;
    const int pi = (pr < 33) ? pr : 32;
    const int qj = (pr < 33) ? 32 : (pr - 33);
    float sa0 = 0.f, sa1 = 0.f, sa2 = 0.f, sa3 = 0.f;
    const int hb = o * 32;
    for (int h8 = hb; h8 < hb + 32; h8 += 8) {
      HU r8, l8;
      r8.v = *(const half8*)&rl[pi][h8];
      l8.v = *(const half8*)&ll[qj][h8];
#pragma unroll
      for (int j = 0; j < 4; ++j) {
        float2 pf = __half22float2(__hmul2(r8.h.p[j], l8.h.p[j]));
        float u0 = __builtin_amdgcn_exp2f(pf.x);
        float u1 = __builtin_amdgcn_exp2f(pf.y);
        float g0 = u0 * fmaf(u0, fmaf(u0, 0.333048f, -0.818328f), 0.991381f);
        float g1 = u1 * fmaf(u1, fmaf(u1, 0.333048f, -0.818328f), 0.991381f);
        float4 wa = *(const float4*)&cw[(h8 + 2 * j) * 4];
        float4 wb = *(const float4*)&cw[(h8 + 2 * j + 1) * 4];
        sa0 = fmaf(-2.f * g0, wa.x, fmaf(-2.f * g1, wb.x, sa0));
        sa1 = fmaf(-2.f * g0, wa.y, fmaf(-2.f * g1, wb.y, sa1));
        sa2 = fmaf(-2.f * g0, wa.z, fmaf(-2.f * g1, wb.z, sa2));
        sa3 = fmaf(-2.f * g0, wa.w, fmaf(-2.f * g1, wb.w, sa3));
      }
    }
    sa0 += __shfl_xor(sa0, 1, 64);
    sa1 += __shfl_xor(sa1, 1, 64);
    sa2 += __shfl_xor(sa2, 1, 64);
    sa3 += __shfl_xor(sa3, 1, 64);
    sa0 += __shfl_xor(sa0, 2, 64);
    sa1 += __shfl_xor(sa1, 2, 64);
    sa2 += __shfl_xor(sa2, 2, 64);
    sa3 += __shfl_xor(sa3, 2, 64);
    if (o == 0) {
      _Float16 h0 = (_Float16)(wsumg[0] + sa0);
      _Float16 h1 = (_Float16)(wsumg[1] + sa1);
      _Float16 h2 = (_Float16)(wsumg[2] + sa2);
      _Float16 h3 = (_Float16)(wsumg[3] + sa3);
      US4 s;
      s.u[0] = *(ushort_t*)&h0; s.u[1] = *(ushort_t*)&h1;
      s.u[2] = *(ushort_t*)&h2; s.u[3] = *(ushort_t*)&h3;
      *(US4*)&sl4[pi][qj][0] = s;
    }
  }
  __syncthreads();

  // phase C: y = cb + s00(iy-1,jj-1)+s01(iy-1,jj)+s10(iy,jj-1)+s11(iy,jj)
  float m = -INFINITY;
  const float cbv = cb[0];
  for (int p = t; p < TILE * TILE; p += 512) {
    int jj = (p & 31) + 1, iy = (p >> 5) + 1;
    float v = cbv + (float)(*(const _Float16*)&sl4[iy - 1][jj - 1][0])
                  + (float)(*(const _Float16*)&sl4[iy - 1][jj][1])
                  + (float)(*(const _Float16*)&sl4[iy][jj - 1][2])
                  + (float)(*(const _Float16*)&sl4[iy][jj][3]);
    m = fmaxf(m, v);
  }
#pragma unroll
  for (int off = 32; off > 0; off >>= 1) m = fmaxf(m, __shfl_down(m, off, 64));
  if ((t & 63) == 0) wred[t >> 6] = m;
  __syncthreads();
  if (t == 0) {
    float mm = wred[0];
#pragma unroll
    for (int i = 1; i < 8; ++i) mm = fmaxf(mm, wred[i]);
    partial[((size_t)b * NT + blockIdx.y) * NT + blockIdx.x] = mm;
  }
}

// ---------------------------------------------------------------------------
// Kernel 3: reduce 16x16 partials per batch, sigmoid, write 4 outputs.
// ---------------------------------------------------------------------------
__global__ __launch_bounds__(64) void finalize(const float* __restrict__ partial,
                                               float* __restrict__ out) {
  const int b = blockIdx.x, t = threadIdx.x;
  float m = -INFINITY;
  for (int p = t; p < NT * NT; p += 64) m = fmaxf(m, partial[b * NT * NT + p]);
#pragma unroll
  for (int off = 32; off > 0; off >>= 1) m = fmaxf(m, __shfl_down(m, off, 64));
  if (t == 0) out[b] = 1.f / (1.f + expf(-m));
}

extern "C" void kernel_launch(void* const* d_in, const int* in_sizes, int n_in,
                              void* d_out, int out_size, void* d_ws, size_t ws_size,
                              hipStream_t stream) {
  const float* rec = (const float*)d_in[0];
  const float* lig = (const float*)d_in[1];
  const float* W1  = (const float*)d_in[2];
  const float* b1  = (const float*)d_in[3];
  const float* cw  = (const float*)d_in[4];   // (1,H,2,2): {w00,w01,w10,w11} per h
  const float* cb  = (const float*)d_in[5];
  float* out = (float*)d_out;

  ushort_t* hid  = (ushort_t*)d_ws;                        // 4096x128 f16 = 1 MB
  float* partial = (float*)(hid + (size_t)2 * BDIM * LDIM * HDIM);  // 1024 f32
  ushort_t* wneg = (ushort_t*)(partial + NT * NT * BDIM);  // 16x128 f16 = 4 KB
  float* wsumg   = (float*)(wneg + 16 * HDIM);             // 4 f32

  gemm_lds<<<dim3(256), 512, 0, stream>>>(rec, lig, W1, b1, cw, hid, wneg, wsumg);
  bilinear_max<<<dim3(NT, NT, BDIM), 512, 0, stream>>>(hid, wneg, wsumg, cw, cb, partial);
  finalize<<<dim3(BDIM), 64, 0, stream>>>(partial, out);
}

// Round 13
// 110.394 us; speedup vs baseline: 1.0555x; 1.0359x over previous
//
#include <hip/hip_runtime.h>
#include <hip/hip_fp16.h>
#include <math.h>

#define BDIM 4
#define LDIM 512
#define EDIM 1024
#define HDIM 128
#define TI   32            // i-tile
#define TJ   64            // j-tile (widened from 32: amortize staging/edge)
#define NTI  16            // 512/TI (blockIdx.y)
#define NTJ  8             // 512/TJ (blockIdx.x)
#define K2   2.885390081777927f   // 2/ln(2)

typedef unsigned short ushort_t;
typedef __attribute__((ext_vector_type(8))) _Float16 half8;
typedef __attribute__((ext_vector_type(4))) float f32x4;

struct __align__(16) H8 { __half2 p[4]; };
union HU { H8 h; half8 v; };
struct __align__(8) US4 { ushort_t u[4]; };

// ---------------------------------------------------------------------------
// Kernel 1 (round-9/10 exact): LDS-staged GEMM, 512-thread blocks.
// hid = relu(emb @ W1 + b1) f16 (rec rows * -K2). 256 blocks = 1 block/CU,
// 8 waves = 2 waves/SIMD. Block 0 also preps wneg[16][128] + wsumg[4].
// ---------------------------------------------------------------------------
__global__ __launch_bounds__(512) void gemm_lds(
    const float* __restrict__ rec, const float* __restrict__ lig,
    const float* __restrict__ W1, const float* __restrict__ b1,
    const float* __restrict__ cw, ushort_t* __restrict__ hid,
    ushort_t* __restrict__ wneg, float* __restrict__ wsumg) {
  __shared__ ushort_t Al[16][1026];        // 32.8 KB, row stride 513 dw (odd)
  __shared__ ushort_t Bl[2][128][130];     // 66.6 KB, row stride 65 dw (odd)
  __shared__ float wp[2][4];

  const int t = threadIdx.x;

  if (blockIdx.x == 0) {                   // fold wneg/wsumg prep into block 0
    if (t < HDIM) {
      float4 w4 = *(const float4*)&cw[t * 4];
      _Float16 h0 = (_Float16)(-2.f * w4.x), h1 = (_Float16)(-2.f * w4.y);
      _Float16 h2 = (_Float16)(-2.f * w4.z), h3 = (_Float16)(-2.f * w4.w);
      wneg[0 * HDIM + t] = *(ushort_t*)&h0;
      wneg[1 * HDIM + t] = *(ushort_t*)&h1;
      wneg[2 * HDIM + t] = *(ushort_t*)&h2;
      wneg[3 * HDIM + t] = *(ushort_t*)&h3;
#pragma unroll
      for (int k = 4; k < 16; ++k) wneg[k * HDIM + t] = 0;
      float4 ws = w4;
#pragma unroll
      for (int off = 32; off > 0; off >>= 1) {
        ws.x += __shfl_down(ws.x, off, 64);
        ws.y += __shfl_down(ws.y, off, 64);
        ws.z += __shfl_down(ws.z, off, 64);
        ws.w += __shfl_down(ws.w, off, 64);
      }
      if ((t & 63) == 0) {
        wp[t >> 6][0] = ws.x; wp[t >> 6][1] = ws.y;
        wp[t >> 6][2] = ws.z; wp[t >> 6][3] = ws.w;
      }
    }
    __syncthreads();
    if (t < 4) wsumg[t] = wp[0][t] + wp[1][t];
  }

  const int r0 = (int)blockIdx.x * 16;     // strip rows r0..r0+15
  const float* abase = (r0 < BDIM * LDIM)
                           ? rec + (size_t)r0 * EDIM
                           : lig + (size_t)(r0 - BDIM * LDIM) * EDIM;

  // ---- stage A strip: 16 rows x 1024 f32 -> f16. thread t: row t>>5,
  // cols (t&31)*4 + p*128 (32 lanes x 16B contiguous per row).
  {
    const int sr = t >> 5, su = t & 31;
    const float* ar = abase + (size_t)sr * EDIM;
#pragma unroll
    for (int p = 0; p < 8; ++p) {
      const int c = su * 4 + p * 128;
      f32x4 v = *(const f32x4*)(ar + c);
      *(__half2*)&Al[sr][c] = __floats2half2_rn(v[0], v[1]);
      *(__half2*)&Al[sr][c + 2] = __floats2half2_rn(v[2], v[3]);
    }
  }

  // ---- stage B chunk 0: rows 0..127 of W1 -> Bl[0] transposed [col][k].
  // thread t: k-pair kp = p*16 + (t>>5), cols (t&31)*4..+3, p in 0..3.
  const int cu4 = (t & 31) * 4, kg = t >> 5;
  {
#pragma unroll
    for (int p = 0; p < 4; ++p) {
      const int kp = p * 16 + kg;
      f32x4 ra = *(const f32x4*)(W1 + (size_t)(2 * kp) * HDIM + cu4);
      f32x4 rb = *(const f32x4*)(W1 + (size_t)(2 * kp + 1) * HDIM + cu4);
#pragma unroll
      for (int i = 0; i < 4; ++i)
        *(__half2*)&Bl[0][cu4 + i][2 * kp] = __floats2half2_rn(ra[i], rb[i]);
    }
  }
  __syncthreads();

  const int w = t >> 6, l = t & 63;        // 8 waves
  const int m = l & 15, q = l >> 4;
  const int tc0 = 16 * w;                  // wave's 16-col tile

  f32x4 acc = {0.f, 0.f, 0.f, 0.f};
  for (int kc = 0; kc < 8; ++kc) {
    const int bb = kc & 1;
    f32x4 sa[4], sb[4];
    if (kc < 7) {                          // prefetch next chunk to regs
      const float* wb = W1 + (size_t)((kc + 1) * 128) * HDIM;
#pragma unroll
      for (int p = 0; p < 4; ++p) {
        const int kp = p * 16 + kg;
        sa[p] = *(const f32x4*)(wb + (size_t)(2 * kp) * HDIM + cu4);
        sb[p] = *(const f32x4*)(wb + (size_t)(2 * kp + 1) * HDIM + cu4);
      }
    }
#pragma unroll
    for (int s = 0; s < 4; ++s) {
      const int kof = s * 32 + q * 8;
      half8 af = *(const half8*)&Al[m][kc * 128 + kof];
      half8 bf = *(const half8*)&Bl[bb][tc0 + m][kof];
      acc = __builtin_amdgcn_mfma_f32_16x16x32_f16(af, bf, acc, 0, 0, 0);
    }
    if (kc < 7) {                          // drain prefetch into other buffer
#pragma unroll
      for (int p = 0; p < 4; ++p) {
        const int kp = p * 16 + kg;
#pragma unroll
        for (int i = 0; i < 4; ++i)
          *(__half2*)&Bl[bb ^ 1][cu4 + i][2 * kp] =
              __floats2half2_rn(sa[p][i], sb[p][i]);
      }
    }
    __syncthreads();
  }

  const float scale = (r0 < BDIM * LDIM) ? -K2 : 1.0f;
  const float bias = b1[tc0 + m];
#pragma unroll
  for (int r = 0; r < 4; ++r) {
    const int row = r0 + q * 4 + r;
    float v = fmaxf(acc[r] + bias, 0.f) * scale;
    ((_Float16*)hid)[(size_t)row * HDIM + tc0 + m] = (_Float16)v;
  }
}

// ---------------------------------------------------------------------------
// Kernel 2: 32x64 y-tile (was 32x32), 512-thread/8-wave blocks, grid
// (8,16,4)=512 -> 2 blocks/CU x 8 waves = 16 waves/CU (same residency as
// round-10 best). LDS 43 KB. Per-cell fixed costs drop: staging rows 0.74x,
// edge pairs 0.75x, total barriers 0.5x; phase B inner loop byte-identical
// per hf-iteration (now 4 iters). launch_bounds(512,4) -> 128 VGPR.
// ---------------------------------------------------------------------------
__global__ __launch_bounds__(512, 4) void bilinear_max(
    const ushort_t* __restrict__ hid, const ushort_t* __restrict__ wneg,
    const float* __restrict__ wsumg, const float* __restrict__ cw,
    const float* __restrict__ cb, float* __restrict__ partial) {
  __shared__ ushort_t rl[TI + 1][130];       // 33 rows, 65-dw stride
  __shared__ ushort_t ll[TJ + 1][130];       // 65 rows
  __shared__ ushort_t sl4[TI + 1][TJ + 2][4];  // f16 taps {s00,s01,s10,s11}
  __shared__ float wred[8];

  const int t = threadIdx.x;
  const int b = blockIdx.z;
  const int ib = (int)blockIdx.y * TI - 1;
  const int jb = (int)blockIdx.x * TJ - 1;
  const int w = t >> 6, l = t & 63;
  const int q = l >> 4, c15 = l & 15;

  half8 wf[4];
#pragma unroll
  for (int c = 0; c < 4; ++c)
    wf[c] = *(const half8*)&wneg[c15 * HDIM + c * 32 + q * 8];
  const float wsum_v = (c15 < 4) ? wsumg[c15] : 0.f;

  // stage 33+65 rows x 16 octets = 1568 units
  H8 z;
  z.p[0] = z.p[1] = z.p[2] = z.p[3] = __floats2half2_rn(0.f, 0.f);
  for (int p = t; p < (TI + TJ + 2) * 16; p += 512) {
    int r = p >> 4, seg = (p & 15) * 8;
    if (r < TI + 1) {
      int i = ib + r;
      H8 v = z;
      if (i >= 0) v = *(const H8*)&hid[((size_t)(b * LDIM + i)) * HDIM + seg];
      *(H8*)&rl[r][seg] = v;
    } else {
      int j = jb + (r - (TI + 1));
      H8 v = z;
      if (j >= 0) v = *(const H8*)&hid[((size_t)((BDIM + b) * LDIM + j)) * HDIM + seg];
      *(H8*)&ll[r - (TI + 1)][seg] = v;
    }
  }
  __syncthreads();

  const __half2 E0 = __float2half2_rn(0.991381f);
  const __half2 E1 = __float2half2_rn(-0.818328f);
  const __half2 E2 = __float2half2_rn(0.333048f);
#define POLYG(U) __hmul2(U, __hfma2(U, __hfma2(U, E2, E1), E0))
#define GCHAIN(GU, RU, LU)                                                    \
  {                                                                           \
    __half2 u0 = h2exp2(__hmul2((RU).h.p[0], (LU).h.p[0]));                   \
    __half2 u1 = h2exp2(__hmul2((RU).h.p[1], (LU).h.p[1]));                   \
    __half2 u2 = h2exp2(__hmul2((RU).h.p[2], (LU).h.p[2]));                   \
    __half2 u3 = h2exp2(__hmul2((RU).h.p[3], (LU).h.p[3]));                   \
    (GU).h.p[0] = POLYG(u0);                                                  \
    (GU).h.p[1] = POLYG(u1);                                                  \
    (GU).h.p[2] = POLYG(u2);                                                  \
    (GU).h.p[3] = POLYG(u3);                                                  \
  }

  // phase B: wave w covers ii in [4w, 4w+4); hf loop over 4 j-halves.
#pragma unroll
  for (int hf = 0; hf < 4; ++hf) {
    const int jj0 = hf << 4;
    HU lu[4];
#pragma unroll
    for (int c = 0; c < 4; ++c)
      lu[c].v = *(const half8*)&ll[jj0 + c15][c * 32 + q * 8];
    const int ii = w * 4;
    f32x4 a0 = {0.f, 0.f, 0.f, 0.f}, a1 = a0, a2 = a0, a3 = a0;
#pragma unroll
    for (int c = 0; c < 4; ++c) {
      HU r0, r1, r2, r3, g0, g1, g2, g3;
      r0.v = *(const half8*)&rl[ii + 0][c * 32 + q * 8];
      r1.v = *(const half8*)&rl[ii + 1][c * 32 + q * 8];
      r2.v = *(const half8*)&rl[ii + 2][c * 32 + q * 8];
      r3.v = *(const half8*)&rl[ii + 3][c * 32 + q * 8];
      GCHAIN(g0, r0, lu[c])
      GCHAIN(g1, r1, lu[c])
      GCHAIN(g2, r2, lu[c])
      GCHAIN(g3, r3, lu[c])
      a0 = __builtin_amdgcn_mfma_f32_16x16x32_f16(g0.v, wf[c], a0, 0, 0, 0);
      a1 = __builtin_amdgcn_mfma_f32_16x16x32_f16(g1.v, wf[c], a1, 0, 0, 0);
      a2 = __builtin_amdgcn_mfma_f32_16x16x32_f16(g2.v, wf[c], a2, 0, 0, 0);
      a3 = __builtin_amdgcn_mfma_f32_16x16x32_f16(g3.v, wf[c], a3, 0, 0, 0);
    }
    if (c15 < 4) {
#pragma unroll
      for (int r = 0; r < 4; ++r) {
        _Float16 h0 = (_Float16)(wsum_v + a0[r]);
        _Float16 h1 = (_Float16)(wsum_v + a1[r]);
        _Float16 h2 = (_Float16)(wsum_v + a2[r]);
        _Float16 h3 = (_Float16)(wsum_v + a3[r]);
        sl4[ii + 0][jj0 + q * 4 + r][c15] = *(ushort_t*)&h0;
        sl4[ii + 1][jj0 + q * 4 + r][c15] = *(ushort_t*)&h1;
        sl4[ii + 2][jj0 + q * 4 + r][c15] = *(ushort_t*)&h2;
        sl4[ii + 3][jj0 + q * 4 + r][c15] = *(ushort_t*)&h3;
      }
    }
  }
#undef GCHAIN
#undef POLYG

  // edge strips (no barrier needed: disjoint sl4 region from phase B).
  // col edge (pi=0..32, qj=64) 33 pairs + row edge (pi=32, qj=0..63) 64
  // pairs = 97 pairs x 4 lanes (32 h each) over threads 0..387.
  if (t < 388) {
    const int pr = t >> 2;
    const int o = t & 3;
    const int pi = (pr < TI + 1) ? pr : TI;
    const int qj = (pr < TI + 1) ? TJ : (pr - (TI + 1));
    float sa0 = 0.f, sa1 = 0.f, sa2 = 0.f, sa3 = 0.f;
    const int hb = o * 32;
    for (int h8 = hb; h8 < hb + 32; h8 += 8) {
      HU r8, l8;
      r8.v = *(const half8*)&rl[pi][h8];
      l8.v = *(const half8*)&ll[qj][h8];
#pragma unroll
      for (int j = 0; j < 4; ++j) {
        float2 pf = __half22float2(__hmul2(r8.h.p[j], l8.h.p[j]));
        float u0 = __builtin_amdgcn_exp2f(pf.x);
        float u1 = __builtin_amdgcn_exp2f(pf.y);
        float g0 = u0 * fmaf(u0, fmaf(u0, 0.333048f, -0.818328f), 0.991381f);
        float g1 = u1 * fmaf(u1, fmaf(u1, 0.333048f, -0.818328f), 0.991381f);
        float4 wa = *(const float4*)&cw[(h8 + 2 * j) * 4];
        float4 wb = *(const float4*)&cw[(h8 + 2 * j + 1) * 4];
        sa0 = fmaf(-2.f * g0, wa.x, fmaf(-2.f * g1, wb.x, sa0));
        sa1 = fmaf(-2.f * g0, wa.y, fmaf(-2.f * g1, wb.y, sa1));
        sa2 = fmaf(-2.f * g0, wa.z, fmaf(-2.f * g1, wb.z, sa2));
        sa3 = fmaf(-2.f * g0, wa.w, fmaf(-2.f * g1, wb.w, sa3));
      }
    }
    sa0 += __shfl_xor(sa0, 1, 64);
    sa1 += __shfl_xor(sa1, 1, 64);
    sa2 += __shfl_xor(sa2, 1, 64);
    sa3 += __shfl_xor(sa3, 1, 64);
    sa0 += __shfl_xor(sa0, 2, 64);
    sa1 += __shfl_xor(sa1, 2, 64);
    sa2 += __shfl_xor(sa2, 2, 64);
    sa3 += __shfl_xor(sa3, 2, 64);
    if (o == 0) {
      _Float16 h0 = (_Float16)(wsumg[0] + sa0);
      _Float16 h1 = (_Float16)(wsumg[1] + sa1);
      _Float16 h2 = (_Float16)(wsumg[2] + sa2);
      _Float16 h3 = (_Float16)(wsumg[3] + sa3);
      US4 s;
      s.u[0] = *(ushort_t*)&h0; s.u[1] = *(ushort_t*)&h1;
      s.u[2] = *(ushort_t*)&h2; s.u[3] = *(ushort_t*)&h3;
      *(US4*)&sl4[pi][qj][0] = s;
    }
  }
  __syncthreads();

  // phase C: y = cb + s00(iy-1,jj-1)+s01(iy-1,jj)+s10(iy,jj-1)+s11(iy,jj)
  float m = -INFINITY;
  const float cbv = cb[0];
  for (int p = t; p < TI * TJ; p += 512) {
    int jj = (p & 63) + 1, iy = (p >> 6) + 1;
    float v = cbv + (float)(*(const _Float16*)&sl4[iy - 1][jj - 1][0])
                  + (float)(*(const _Float16*)&sl4[iy - 1][jj][1])
                  + (float)(*(const _Float16*)&sl4[iy][jj - 1][2])
                  + (float)(*(const _Float16*)&sl4[iy][jj][3]);
    m = fmaxf(m, v);
  }
#pragma unroll
  for (int off = 32; off > 0; off >>= 1) m = fmaxf(m, __shfl_down(m, off, 64));
  if ((t & 63) == 0) wred[t >> 6] = m;
  __syncthreads();
  if (t == 0) {
    float mm = wred[0];
#pragma unroll
    for (int i = 1; i < 8; ++i) mm = fmaxf(mm, wred[i]);
    partial[((size_t)b * NTI + blockIdx.y) * NTJ + blockIdx.x] = mm;
  }
}

// ---------------------------------------------------------------------------
// Kernel 3: reduce 16x8 partials per batch, sigmoid, write 4 outputs.
// ---------------------------------------------------------------------------
__global__ __launch_bounds__(64) void finalize(const float* __restrict__ partial,
                                               float* __restrict__ out) {
  const int b = blockIdx.x, t = threadIdx.x;
  float m = -INFINITY;
  for (int p = t; p < NTI * NTJ; p += 64) m = fmaxf(m, partial[b * NTI * NTJ + p]);
#pragma unroll
  for (int off = 32; off > 0; off >>= 1) m = fmaxf(m, __shfl_down(m, off, 64));
  if (t == 0) out[b] = 1.f / (1.f + expf(-m));
}

extern "C" void kernel_launch(void* const* d_in, const int* in_sizes, int n_in,
                              void* d_out, int out_size, void* d_ws, size_t ws_size,
                              hipStream_t stream) {
  const float* rec = (const float*)d_in[0];
  const float* lig = (const float*)d_in[1];
  const float* W1  = (const float*)d_in[2];
  const float* b1  = (const float*)d_in[3];
  const float* cw  = (const float*)d_in[4];   // (1,H,2,2): {w00,w01,w10,w11} per h
  const float* cb  = (const float*)d_in[5];
  float* out = (float*)d_out;

  ushort_t* hid  = (ushort_t*)d_ws;                        // 4096x128 f16 = 1 MB
  float* partial = (float*)(hid + (size_t)2 * BDIM * LDIM * HDIM);  // 512 f32
  ushort_t* wneg = (ushort_t*)(partial + NTI * NTJ * BDIM);  // 16x128 f16 = 4 KB
  float* wsumg   = (float*)(wneg + 16 * HDIM);             // 4 f32

  gemm_lds<<<dim3(256), 512, 0, stream>>>(rec, lig, W1, b1, cw, hid, wneg, wsumg);
  bilinear_max<<<dim3(NTJ, NTI, BDIM), 512, 0, stream>>>(hid, wneg, wsumg, cw, cb, partial);
  finalize<<<dim3(BDIM), 64, 0, stream>>>(partial, out);
}